// Round 2
// baseline (1193.804 us; speedup 1.0000x reference)
//
#include <hip/hip_runtime.h>
#include <stdint.h>

// Problem constants (fixed by the reference)
#define NROWS 1000000
#define DDIM  128
#define NCLS  1000

// accum decomposition: 8 dim-groups x 16 floats (64B line per row-slice),
// 64 row-blocks per group -> 512 blocks = 256 CUs x 2 blocks/CU (64KB LDS each).
#define DG    8
#define BPG   64
#define RPB   ((NROWS + BPG - 1) / BPG)   // 15625 rows per block
#define TPB   1024

typedef float f4 __attribute__((ext_vector_type(4)));

// ws layout (4-byte words):
//   [0, 128000)        sums  (float, c*128 + d)
//   [128000, 129000)   counts (int)
//   [129024, 129152)   var_d (float)
#define WS_SUMS   0
#define WS_COUNTS 128000
#define WS_VARD   129024

__global__ __launch_bounds__(256) void zero_kernel(float* __restrict__ sums,
                                                   int* __restrict__ counts) {
    int t = blockIdx.x * 256 + threadIdx.x;
    if (t < NCLS * DDIM / 4) {
        f4 z = {0.0f, 0.0f, 0.0f, 0.0f};
        ((f4*)sums)[t] = z;
    }
    int u = t - NCLS * DDIM / 4;
    if (u >= 0 && u < NCLS) counts[u] = 0;
}

// Per-block LDS histogram of labels -> global counts.
__global__ __launch_bounds__(256) void hist_kernel(const int* __restrict__ labels,
                                                   int* __restrict__ counts) {
    __shared__ int h[NCLS];
    for (int e = threadIdx.x; e < NCLS; e += 256) h[e] = 0;
    __syncthreads();
    for (int r = blockIdx.x * 256 + threadIdx.x; r < NROWS; r += 256 * 256)
        atomicAdd(&h[labels[r]], 1);
    __syncthreads();
    for (int e = threadIdx.x; e < NCLS; e += 256) atomicAdd(&counts[e], h[e]);
}

// Streaming class-sum accumulation. Block (g,b): rows [b*RPB, (b+1)*RPB),
// dims [g*16, g*16+16). Each row-slice is one aligned 64B line -> fully
// coalesced, every fetched byte used, embeddings read exactly once device-wide.
// LDS accumulator part[c][j] stored at j^(c&15) to spread the 16-float class
// stride across banks (random classes -> ~2-way, free).
__global__ __launch_bounds__(TPB) void accum_kernel(const float* __restrict__ emb,
                                                    const int* __restrict__ labels,
                                                    float* __restrict__ sums) {
    __shared__ float part[NCLS * 16];   // 64 KB
    const int g  = blockIdx.x & (DG - 1);   // adjacent bids = same rows, diff dims
    const int b  = blockIdx.x / DG;
    const int q  = threadIdx.x & 3;         // f4 slot within the 16-float slice
    const int tr = threadIdx.x >> 2;        // row offset within iteration (0..255)

    f4 zero = {0.0f, 0.0f, 0.0f, 0.0f};
    f4* part4 = (f4*)part;
    for (int e = threadIdx.x; e < NCLS * 4; e += TPB) part4[e] = zero;
    __syncthreads();

    const f4* emb4 = (const f4*)emb;
    const int r0 = b * RPB;
    const int r1 = (r0 + RPB < NROWS) ? (r0 + RPB) : NROWS;
    const int iters = (r1 - r0 + (TPB / 4) - 1) / (TPB / 4);

    // 2-deep software pipeline: next row-slice + label in flight during LDS adds.
    int r = r0 + tr;
    f4 v = zero;
    int c = 0;
    bool val = (r < r1);
    if (val) {
        v = __builtin_nontemporal_load(&emb4[(size_t)r * 32 + g * 4 + q]);
        c = labels[r];
    }
    for (int it = 0; it < iters; ++it) {
        const int rn = r + TPB / 4;
        f4 vn = zero;
        int cn = 0;
        const bool valn = (rn < r1);
        if (valn) {
            vn = __builtin_nontemporal_load(&emb4[(size_t)rn * 32 + g * 4 + q]);
            cn = labels[rn];
        }
        if (val) {
            const int m = c & 15, base = c * 16, j0 = q * 4;
            unsafeAtomicAdd(&part[base + ((j0 + 0) ^ m)], v.x);
            unsafeAtomicAdd(&part[base + ((j0 + 1) ^ m)], v.y);
            unsafeAtomicAdd(&part[base + ((j0 + 2) ^ m)], v.z);
            unsafeAtomicAdd(&part[base + ((j0 + 3) ^ m)], v.w);
        }
        v = vn; c = cn; val = valn; r = rn;
    }

    __syncthreads();
    // Merge block partial into global sums (64 contenders per address).
    for (int e = threadIdx.x; e < NCLS * 16; e += TPB) {
        const int cc = e >> 4, j = e & 15;
        unsafeAtomicAdd(&sums[cc * DDIM + g * 16 + j], part[cc * 16 + (j ^ (cc & 15))]);
    }
}

// One block per dim d: variance over 1000 class means (ddof=1) -> var_d[d].
__global__ __launch_bounds__(256) void var_kernel(const float* __restrict__ sums,
                                                  const int* __restrict__ counts,
                                                  float* __restrict__ var_d) {
    const int d = blockIdx.x;
    float s1 = 0.0f, s2 = 0.0f;
    for (int c = threadIdx.x; c < NCLS; c += 256) {
        float mv = sums[c * DDIM + d] / (float)counts[c];
        s1 += mv;
        s2 += mv * mv;
    }
    #pragma unroll
    for (int off = 32; off; off >>= 1) {
        s1 += __shfl_down(s1, off);
        s2 += __shfl_down(s2, off);
    }
    __shared__ float p1[4], p2[4];
    int wave = threadIdx.x >> 6, lane = threadIdx.x & 63;
    if (lane == 0) { p1[wave] = s1; p2[wave] = s2; }
    __syncthreads();
    if (threadIdx.x == 0) {
        float t1 = p1[0] + p1[1] + p1[2] + p1[3];
        float t2 = p2[0] + p2[1] + p2[2] + p2[3];
        var_d[d] = (t2 - t1 * t1 / (float)NCLS) / (float)(NCLS - 1);
    }
}

__global__ __launch_bounds__(64) void final_kernel(const float* __restrict__ var_d,
                                                   float* __restrict__ out) {
    float s = var_d[threadIdx.x] + var_d[threadIdx.x + 64];
    #pragma unroll
    for (int off = 32; off; off >>= 1) s += __shfl_down(s, off);
    if (threadIdx.x == 0) out[0] = -s / (float)DDIM;
}

extern "C" void kernel_launch(void* const* d_in, const int* in_sizes, int n_in,
                              void* d_out, int out_size, void* d_ws, size_t ws_size,
                              hipStream_t stream) {
    const float* emb    = (const float*)d_in[0];
    const int*   labels = (const int*)d_in[1];
    float* wsf    = (float*)d_ws;
    int*   wsi    = (int*)d_ws;
    float* sums   = wsf + WS_SUMS;
    int*   counts = wsi + WS_COUNTS;
    float* var_d  = wsf + WS_VARD;
    float* out    = (float*)d_out;

    hipLaunchKernelGGL(zero_kernel, dim3((NCLS * DDIM / 4 + NCLS + 255) / 256), dim3(256),
                       0, stream, sums, counts);
    hipLaunchKernelGGL(hist_kernel, dim3(256), dim3(256), 0, stream, labels, counts);
    hipLaunchKernelGGL(accum_kernel, dim3(DG * BPG), dim3(TPB), 0, stream, emb, labels, sums);
    hipLaunchKernelGGL(var_kernel, dim3(DDIM), dim3(256), 0, stream, sums, counts, var_d);
    hipLaunchKernelGGL(final_kernel, dim3(1), dim3(64), 0, stream, var_d, out);
}

// Round 3
// 861.426 us; speedup vs baseline: 1.3858x; 1.3858x over previous
//
#include <hip/hip_runtime.h>
#include <stdint.h>

// Problem constants
#define NROWS 1000000
#define DDIM  128
#define NCLS  1000
#define SUMROWS 1024                 // class rows incl. sentinel 1023

// gather decomposition: 512 blocks x 8 waves = 4096 waves, 256 entries each
#define GBLOCKS 512
#define NWAVES  (GBLOCKS * 8)
#define WCHUNK  256
#define TOTPAD  (NWAVES * WCHUNK)    // 1048576 >= NROWS, tail = sentinels

typedef float f4 __attribute__((ext_vector_type(4)));

// ws layout (4-byte words):
//   [0, 131072)            sums   (float, c*128 + d; rows 1000..1023 sentinel)
//   [131072, 132096)       counts (int)
//   [132096, 133120)       cursor (int)
//   [133120, 133248)       var_d  (float)
//   [133376, 133376+TOTPAD) entries (u32: row | class<<20)
#define WS_SUMS    0
#define WS_COUNTS  131072
#define WS_CURSOR  132096
#define WS_VARD    133120
#define WS_ENTRIES 133376

__global__ __launch_bounds__(256) void zero_kernel(float* __restrict__ sums,
                                                   int* __restrict__ counts) {
    int t = blockIdx.x * 256 + threadIdx.x;   // 128 blocks -> 32768 threads
    f4 z = {0.0f, 0.0f, 0.0f, 0.0f};
    ((f4*)sums)[t] = z;                        // 32768 f4 = 131072 floats
    if (t < SUMROWS) counts[t] = 0;
}

// Per-block LDS histogram of labels -> global counts. LDS atomics here total
// only 1M lane-ops (~5 us device-wide).
__global__ __launch_bounds__(256) void hist_kernel(const int* __restrict__ labels,
                                                   int* __restrict__ counts) {
    __shared__ int h[NCLS];
    for (int e = threadIdx.x; e < NCLS; e += 256) h[e] = 0;
    __syncthreads();
    for (int r = blockIdx.x * 256 + threadIdx.x; r < NROWS; r += 256 * 256)
        atomicAdd(&h[labels[r]], 1);
    __syncthreads();
    for (int e = threadIdx.x; e < NCLS; e += 256) atomicAdd(&counts[e], h[e]);
}

// Exclusive prefix over counts -> dense bucket bases; fill sentinel tail.
__global__ __launch_bounds__(1024) void scan_kernel(const int* __restrict__ counts,
                                                    int* __restrict__ cursor,
                                                    unsigned* __restrict__ entries) {
    if (threadIdx.x == 0) {
        int run = 0;
        for (int c = 0; c < NCLS; ++c) { cursor[c] = run; run += counts[c]; }
    }
    for (int i = NROWS + threadIdx.x; i < TOTPAD; i += 1024)
        entries[i] = (1023u << 20);          // sentinel class 1023, row 0
}

// Class-sort: write packed (row | class<<20) into dense class-ordered list.
__global__ __launch_bounds__(256) void scatter_kernel(const int* __restrict__ labels,
                                                      int* __restrict__ cursor,
                                                      unsigned* __restrict__ entries) {
    for (int r = blockIdx.x * 256 + threadIdx.x; r < NROWS; r += 1024 * 256) {
        int lbl = labels[r];
        int pos = atomicAdd(&cursor[lbl], 1);
        entries[pos] = (unsigned)r | ((unsigned)lbl << 20);
    }
}

// Balanced gather + register accumulation. Each wave owns 256 consecutive
// sorted entries; half-wave (32 lanes x f4) covers one 512B row. Runs of the
// same class accumulate in a register f4 (plain VALU adds -- no LDS atomics);
// flush to global f32 atomics only on run boundaries (~2.5 per wave).
// Correct for ANY entry order (sorting only reduces flush count).
__global__ __launch_bounds__(512, 2) void gather_kernel(const float* __restrict__ emb,
                                                        const unsigned* __restrict__ entries,
                                                        float* __restrict__ sums) {
    const f4* emb4 = (const f4*)emb;
    const int wid  = blockIdx.x * 8 + (threadIdx.x >> 6);
    const int lane = threadIdx.x & 63;
    const int h    = lane >> 5;      // which entry of the pair
    const int q    = lane & 31;      // dims q*4 .. q*4+3
    const int wbase = wid * WCHUNK;

    f4 acc = {0.0f, 0.0f, 0.0f, 0.0f};
    unsigned cur = 0xFFFFFFFFu;

    for (int b = 0; b < WCHUNK / 64; ++b) {
        unsigned pk = entries[wbase + b * 64 + lane];   // 64 entries in regs
        #pragma unroll
        for (int g = 0; g < 4; ++g) {
            unsigned pks[8];
            f4 vv[8];
            #pragma unroll
            for (int u = 0; u < 8; ++u) {
                pks[u] = __shfl((int)pk, g * 16 + 2 * u + h);
                vv[u]  = __builtin_nontemporal_load(
                             &emb4[(size_t)(pks[u] & 0xFFFFFu) * 32 + q]);
            }
            #pragma unroll
            for (int u = 0; u < 8; ++u) {
                unsigned c = pks[u] >> 20;
                if (c != cur) {                 // run boundary (rare)
                    if (cur < NCLS) {
                        unsafeAtomicAdd(&sums[cur * DDIM + q * 4 + 0], acc.x);
                        unsafeAtomicAdd(&sums[cur * DDIM + q * 4 + 1], acc.y);
                        unsafeAtomicAdd(&sums[cur * DDIM + q * 4 + 2], acc.z);
                        unsafeAtomicAdd(&sums[cur * DDIM + q * 4 + 3], acc.w);
                    }
                    f4 z = {0.0f, 0.0f, 0.0f, 0.0f};
                    acc = z;
                    cur = c;
                }
                acc += vv[u];
            }
        }
    }
    if (cur < NCLS) {
        unsafeAtomicAdd(&sums[cur * DDIM + q * 4 + 0], acc.x);
        unsafeAtomicAdd(&sums[cur * DDIM + q * 4 + 1], acc.y);
        unsafeAtomicAdd(&sums[cur * DDIM + q * 4 + 2], acc.z);
        unsafeAtomicAdd(&sums[cur * DDIM + q * 4 + 3], acc.w);
    }
}

// One block per dim d: variance over 1000 class means (ddof=1) -> var_d[d].
__global__ __launch_bounds__(256) void var_kernel(const float* __restrict__ sums,
                                                  const int* __restrict__ counts,
                                                  float* __restrict__ var_d) {
    const int d = blockIdx.x;
    float s1 = 0.0f, s2 = 0.0f;
    for (int c = threadIdx.x; c < NCLS; c += 256) {
        float mv = sums[c * DDIM + d] / (float)counts[c];
        s1 += mv;
        s2 += mv * mv;
    }
    #pragma unroll
    for (int off = 32; off; off >>= 1) {
        s1 += __shfl_down(s1, off);
        s2 += __shfl_down(s2, off);
    }
    __shared__ float p1[4], p2[4];
    int wave = threadIdx.x >> 6, lane = threadIdx.x & 63;
    if (lane == 0) { p1[wave] = s1; p2[wave] = s2; }
    __syncthreads();
    if (threadIdx.x == 0) {
        float t1 = p1[0] + p1[1] + p1[2] + p1[3];
        float t2 = p2[0] + p2[1] + p2[2] + p2[3];
        var_d[d] = (t2 - t1 * t1 / (float)NCLS) / (float)(NCLS - 1);
    }
}

__global__ __launch_bounds__(64) void final_kernel(const float* __restrict__ var_d,
                                                   float* __restrict__ out) {
    float s = var_d[threadIdx.x] + var_d[threadIdx.x + 64];
    #pragma unroll
    for (int off = 32; off; off >>= 1) s += __shfl_down(s, off);
    if (threadIdx.x == 0) out[0] = -s / (float)DDIM;
}

extern "C" void kernel_launch(void* const* d_in, const int* in_sizes, int n_in,
                              void* d_out, int out_size, void* d_ws, size_t ws_size,
                              hipStream_t stream) {
    const float* emb    = (const float*)d_in[0];
    const int*   labels = (const int*)d_in[1];
    float*    wsf     = (float*)d_ws;
    int*      wsi     = (int*)d_ws;
    float*    sums    = wsf + WS_SUMS;
    int*      counts  = wsi + WS_COUNTS;
    int*      cursor  = wsi + WS_CURSOR;
    float*    var_d   = wsf + WS_VARD;
    unsigned* entries = (unsigned*)d_ws + WS_ENTRIES;
    float*    out     = (float*)d_out;

    hipLaunchKernelGGL(zero_kernel, dim3(128), dim3(256), 0, stream, sums, counts);
    hipLaunchKernelGGL(hist_kernel, dim3(256), dim3(256), 0, stream, labels, counts);
    hipLaunchKernelGGL(scan_kernel, dim3(1), dim3(1024), 0, stream, counts, cursor, entries);
    hipLaunchKernelGGL(scatter_kernel, dim3(1024), dim3(256), 0, stream, labels, cursor, entries);
    hipLaunchKernelGGL(gather_kernel, dim3(GBLOCKS), dim3(512), 0, stream, emb, entries, sums);
    hipLaunchKernelGGL(var_kernel, dim3(DDIM), dim3(256), 0, stream, sums, counts, var_d);
    hipLaunchKernelGGL(final_kernel, dim3(1), dim3(64), 0, stream, var_d, out);
}